// Round 4
// baseline (20727.127 us; speedup 1.0000x reference)
//
#include <hip/hip_runtime.h>
#include <hip/hip_bf16.h>

typedef __bf16 bf16x8 __attribute__((ext_vector_type(8)));
typedef float  f32x4  __attribute__((ext_vector_type(4)));
typedef unsigned short u16;
typedef unsigned int   u32;

#define SEQ   512
#define BATCH 64
#define INP   1024
#define HID   1024
#define NBLK  64

// ---- workspace layout (bytes) — identical footprint to round 3 (proven) ----
// wc    : 4096*2048 u16      = 16777216   NEW LAYOUT: [c][g][j][k] — block c's
//                                          256KB slice contiguous at c*131072 elems
// hseq  : 513*64*1024 u16    = 67239936   (h[t] gets its OWN buffer -> no stale L2)
// bias  : 4096 f32           = 16384
// flags : 64 * 32 u32        = 8192       (per-block step counter, 128B apart)
#define WC_OFF    0ull
#define HSEQ_OFF  (WC_OFF + 16777216ull)
#define BIAS_OFF  (HSEQ_OFF + 67239936ull)
#define FLAGS_OFF (BIAS_OFF + 16384ull)

__device__ __forceinline__ u16 f2bf(float f) {
    u32 u = __float_as_uint(f);
    u = (u + 0x7FFFu + ((u >> 16) & 1u)) >> 16;
    return (u16)u;
}

__device__ __forceinline__ bf16x8 ld8(const u16* p) {
    return *reinterpret_cast<const bf16x8*>(p);
}

// 8 consecutive fp32 -> bf16x8 (RNE), via packed cvt
__device__ __forceinline__ bf16x8 cvt8(const float* p) {
    float4 lo = *reinterpret_cast<const float4*>(p);
    float4 hi = *reinterpret_cast<const float4*>(p + 4);
    union { __hip_bfloat162 h2[4]; bf16x8 v; } u;
    u.h2[0] = __float22bfloat162_rn(float2{lo.x, lo.y});
    u.h2[1] = __float22bfloat162_rn(float2{lo.z, lo.w});
    u.h2[2] = __float22bfloat162_rn(float2{hi.x, hi.y});
    u.h2[3] = __float22bfloat162_rn(float2{hi.z, hi.w});
    return u.v;
}

__device__ __forceinline__ float sigmoidf_fast(float x) {
    return 1.0f / (1.0f + __expf(-x));
}
__device__ __forceinline__ float tanhf_fast(float x) {
    return 2.0f / (1.0f + __expf(-2.0f * x)) - 1.0f;
}

// ---------------- prep: weights->bf16 (blocked layout), bias, h0, flags -----
__global__ void lstm_prep(const float* __restrict__ wih,
                          const float* __restrict__ whh,
                          const float* __restrict__ bih,
                          const float* __restrict__ bhh,
                          u16* __restrict__ wc, u16* __restrict__ hseq,
                          float* __restrict__ bias, u32* __restrict__ flags) {
    const long long NW = 8388608ll;    // wc elements (4096*2048)
    const long long NB = 4096ll;
    const long long NH = 65536ll;      // h[0] buffer
    const long long NF = 2048ll;       // flags area (64*32 u32)
    const long long total = NW + NB + NH + NF;
    long long stride = (long long)gridDim.x * blockDim.x;
    for (long long i = (long long)blockIdx.x * blockDim.x + threadIdx.x;
         i < total; i += stride) {
        if (i < NW) {
            // dst layout: [c (6b)][g (2b)][j (4b)][k (11b)]
            long long k = i & 2047;
            long long rowslot = i >> 11;       // 0..4095
            long long c = rowslot >> 6;
            long long g = (rowslot >> 4) & 3;
            long long j = rowslot & 15;
            long long srcrow = g * 1024 + c * 16 + j;
            float v = (k < 1024) ? wih[srcrow * 1024 + k]
                                 : whh[srcrow * 1024 + (k - 1024)];
            wc[i] = f2bf(v);
        } else if (i < NW + NB) {
            long long j = i - NW;
            bias[j] = bih[j] + bhh[j];
        } else if (i < NW + NB + NH) {
            hseq[i - NW - NB] = 0;
        } else {
            flags[i - NW - NB - NH] = 0;
        }
    }
}

// ---------------- persistent recurrence ----------------
// 64 blocks x 1024 threads (16 waves = 4 waves/SIMD for latency hiding).
// Block c owns gate-cols [16c,16c+16) x 4 gates. Wave (midx,kidx):
//   M-rows [16*midx, 16*midx+16), K-slice [256*kidx, 256*kidx+256) of BOTH
//   the x-part (fp32 x, cvt on the fly, pre-barrier) and the h-part.
// Quarter-barrier: wave kidx only needs h-cols [256*kidx,+256) = producers
// flags[16*kidx .. 16*kidx+16).
// Memory model (proven r3): h[t] fresh buffer each step, WT agent u32 stores,
// vmcnt(0)+syncthreads release, relaxed flag publish. No cache-wide fences.
__global__ __launch_bounds__(1024, 4) void lstm_rec(
    const float* __restrict__ x, const u16* __restrict__ wc,
    const float* __restrict__ bias, const float* __restrict__ km,
    u16* __restrict__ hseq, float* __restrict__ out,
    u32* __restrict__ flags, const int* __restrict__ trainp) {

    __shared__ float part[4][4][BATCH][16];  // [kidx][gate][b][j] = 64 KB

    const int tid  = threadIdx.x;
    const int w16  = tid >> 6;          // 0..15
    const int kidx = w16 & 3;
    const int midx = w16 >> 2;
    const int lane = tid & 63;
    const int quad = lane >> 4;
    const int l16  = lane & 15;
    const int cu   = blockIdx.x;        // 0..63
    const int col0 = cu * 16;

    const int training = trainp[0];
    const float scale = training ? (1.0f / 0.9f) : 1.0f;

    // B (weights), blocked layout: elem ((c*64 + g*16 + j)*2048 + k)
    // this wave: j = l16; x-part k = kidx*256 + kk*32 + quad*8; h-part +1024.
    const u16* wbx = wc + (size_t)cu * 131072 + (size_t)l16 * 2048
                        + (size_t)kidx * 256 + (size_t)quad * 8;
    const u16* wbh = wbx + 1024;

    // A rows: b = 16*midx + l16
    const size_t aRowOff = (size_t)(midx * 16 + l16) * 1024
                         + (size_t)kidx * 256 + (size_t)quad * 8;

    // cell-update mapping: 1 element/thread: b = tid>>4, j = tid&15
    const int cb = tid >> 4;
    const int cj = tid & 15;
    float bi[4];
    #pragma unroll
    for (int g = 0; g < 4; ++g)
        bi[g] = bias[g * 1024 + col0 + cj];

    float creg = 0.f;

    #pragma unroll 1
    for (int t = 0; t < SEQ; ++t) {
        // keep-mask prefetch: cold HBM load, max lead time
        float kmv = km[(size_t)t * 65536 + (size_t)cb * 1024 + col0 + cj];

        f32x4 acc[4];   // [gate]
        #pragma unroll
        for (int g = 0; g < 4; ++g)
            acc[g] = (f32x4){0.f, 0.f, 0.f, 0.f};

        // ---- x-part (no grid dependency; overlaps other blocks' publish) ----
        {
            const float* Arow = x + (size_t)t * (BATCH * INP) + aRowOff;
            #pragma unroll 4
            for (int kk = 0; kk < 8; ++kk) {
                bf16x8 afr = cvt8(Arow + kk * 32);
                bf16x8 bfr[4];
                #pragma unroll
                for (int g = 0; g < 4; ++g)
                    bfr[g] = ld8(wbx + (size_t)g * 32768 + kk * 32);
                #pragma unroll
                for (int g = 0; g < 4; ++g)
                    acc[g] = __builtin_amdgcn_mfma_f32_16x16x32_bf16(
                        afr, bfr[g], acc[g], 0, 0, 0);
            }
        }

        // ---- quarter-barrier: wait for MY 16 h-producers only ----
        if (t > 0) {
            const u32* fl = flags + (((u32)(kidx * 16 + l16)) << 5);
            while (true) {
                u32 f = __hip_atomic_load(fl, __ATOMIC_RELAXED,
                                          __HIP_MEMORY_SCOPE_AGENT);
                if (__ballot((int)f >= t) == 0xFFFFFFFFFFFFFFFFull) break;
                __builtin_amdgcn_s_sleep(1);
            }
            asm volatile("" ::: "memory");   // block compiler hoist of h loads
        }

        // ---- h-part ----
        {
            const u16* Hrow = hseq + (size_t)t * 65536 + aRowOff;
            #pragma unroll 4
            for (int kk = 0; kk < 8; ++kk) {
                bf16x8 afr = ld8(Hrow + kk * 32);
                bf16x8 bfr[4];
                #pragma unroll
                for (int g = 0; g < 4; ++g)
                    bfr[g] = ld8(wbh + (size_t)g * 32768 + kk * 32);
                #pragma unroll
                for (int g = 0; g < 4; ++g)
                    acc[g] = __builtin_amdgcn_mfma_f32_16x16x32_bf16(
                        afr, bfr[g], acc[g], 0, 0, 0);
            }
        }

        // C layout: col = lane&15, row = quad*4 + reg
        #pragma unroll
        for (int g = 0; g < 4; ++g)
            #pragma unroll
            for (int r = 0; r < 4; ++r)
                part[kidx][g][midx * 16 + quad * 4 + r][l16] = acc[g][r];

        __syncthreads();

        // ---- cell update: 1 element/thread ----
        u16* hout = hseq + (size_t)(t + 1) * 65536;
        {
            float gi = part[0][0][cb][cj] + part[1][0][cb][cj]
                     + part[2][0][cb][cj] + part[3][0][cb][cj] + bi[0];
            float gf = part[0][1][cb][cj] + part[1][1][cb][cj]
                     + part[2][1][cb][cj] + part[3][1][cb][cj] + bi[1];
            float gg = part[0][2][cb][cj] + part[1][2][cb][cj]
                     + part[2][2][cb][cj] + part[3][2][cb][cj] + bi[2];
            float go = part[0][3][cb][cj] + part[1][3][cb][cj]
                     + part[2][3][cb][cj] + part[3][3][cb][cj] + bi[3];

            float ig = sigmoidf_fast(gi);
            float fg = sigmoidf_fast(gf);
            float gt = tanhf_fast(gg);
            float og = sigmoidf_fast(go);

            float cv = fg * creg + ig * gt;
            creg = cv;
            float hv = og * tanhf_fast(cv);
            if (training) hv = hv * kmv * scale;

            // pack neighbor pair (j, j^1) into one u32 WT store from even lane
            u32 mybits = (u32)f2bf(hv);
            u32 nbbits = (u32)__shfl_xor((int)mybits, 1);
            if ((tid & 1) == 0) {
                u32 packed = mybits | (nbbits << 16);
                __hip_atomic_store((u32*)(hout + (size_t)cb * 1024 + col0 + cj),
                                   packed, __ATOMIC_RELAXED,
                                   __HIP_MEMORY_SCOPE_AGENT);
            }
            if (t == SEQ - 1)
                out[cb * 1024 + col0 + cj] = hv;
        }

        // ---- arrive: my stores acked at coherent point, then publish ----
        asm volatile("s_waitcnt vmcnt(0)" ::: "memory");
        __syncthreads();   // all waves' stores drained + part[] reads done
        if (tid == 0) {
            __hip_atomic_store(flags + ((u32)cu << 5), (u32)(t + 1),
                               __ATOMIC_RELAXED, __HIP_MEMORY_SCOPE_AGENT);
        }
    }
}

extern "C" void kernel_launch(void* const* d_in, const int* in_sizes, int n_in,
                              void* d_out, int out_size, void* d_ws, size_t ws_size,
                              hipStream_t stream) {
    const float* x   = (const float*)d_in[0];
    const float* km  = (const float*)d_in[1];
    const float* wih = (const float*)d_in[2];
    const float* whh = (const float*)d_in[3];
    const float* bih = (const float*)d_in[4];
    const float* bhh = (const float*)d_in[5];
    const int*   tr  = (const int*)d_in[6];
    float* out = (float*)d_out;

    char* ws = (char*)d_ws;
    u16*   wc    = (u16*)(ws + WC_OFF);
    u16*   hseq  = (u16*)(ws + HSEQ_OFF);
    float* bias  = (float*)(ws + BIAS_OFF);
    u32*   flags = (u32*)(ws + FLAGS_OFF);

    lstm_prep<<<dim3(1024), dim3(256), 0, stream>>>(wih, whh, bih, bhh,
                                                    wc, hseq, bias, flags);
    lstm_rec<<<dim3(NBLK), dim3(1024), 0, stream>>>(x, wc, bias, km, hseq,
                                                    out, flags, tr);
}